// Round 1
// baseline (30676.865 us; speedup 1.0000x reference)
//
#include <hip/hip_runtime.h>

// ============================================================================
// Neural CDE forward, MI355X.
// B=256, L=1024, I=16, H=128, W=512, O=4.
//
// Strategy: 16 clusters x 16 blocks (256 blocks, 1/CU). Cluster owns 16 batch
// rows; the recurrence runs fully on-chip. Each block holds a COLUMN SLICE of
// Wf1/Wf2/Wf3 permanently in VGPRs as MFMA B-fragments (bf16), so per-step
// weight traffic is ZERO. Per step, only activations (y: 4KB, h1/h2: 16KB per
// cluster) move through global memory between the cluster's blocks, with
// agent-scope release/acquire barriers (placement-independent correctness).
// ============================================================================

constexpr int LQ = 1024, IQ = 16, HQ = 128, WQ = 512, OQ = 4;
constexpr int CBLK = 16;   // blocks per cluster
constexpr int THREADS = 512;

typedef __attribute__((ext_vector_type(8))) short bf16x8;
typedef __attribute__((ext_vector_type(4))) float f32x4;

#define MFMA16(a, b, c) __builtin_amdgcn_mfma_f32_16x16x32_bf16((a), (b), (c), 0, 0, 0)

__device__ __forceinline__ unsigned short f2bf(float f) {
  unsigned u = __builtin_bit_cast(unsigned, f);
  u += 0x7FFFu + ((u >> 16) & 1u);           // round-nearest-even
  return (unsigned short)(u >> 16);
}
__device__ __forceinline__ float bf2f(unsigned short h) {
  unsigned u = ((unsigned)h) << 16;
  return __builtin_bit_cast(float, u);
}

// B-fragment for mfma_f32_16x16x32_bf16: lane holds B[k0+8*(lane>>4)+j][n0+(lane&15)]
__device__ __forceinline__ bf16x8 load_bfrag(const float* W, int N, int k0, int n0, int lane) {
  const int col = n0 + (lane & 15);
  const int kb  = k0 + 8 * (lane >> 4);
  bf16x8 v;
#pragma unroll
  for (int j = 0; j < 8; ++j) v[j] = (short)f2bf(W[(kb + j) * N + col]);
  return v;
}

// Cluster barrier: monotonic counter, agent scope. Release fence pushes this
// block's stores past its XCD L2; acquire fence invalidates so subsequent
// plain loads see other blocks' data. Weights live in registers -> immune.
__device__ __forceinline__ void cluster_barrier(unsigned* cnt, unsigned target) {
  __syncthreads();
  if (threadIdx.x == 0) {
    __builtin_amdgcn_fence(__ATOMIC_RELEASE, "agent");
    __hip_atomic_fetch_add(cnt, 1u, __ATOMIC_RELAXED, __HIP_MEMORY_SCOPE_AGENT);
    while (__hip_atomic_load(cnt, __ATOMIC_RELAXED, __HIP_MEMORY_SCOPE_AGENT) < target)
      __builtin_amdgcn_s_sleep(1);
    __builtin_amdgcn_fence(__ATOMIC_ACQUIRE, "agent");
  }
  __syncthreads();
}

// ---- LDS pool layout (static 52032 B) ----
constexpr int OFF_H2S = 0;       // ushort h2s[16][520]  (padded, bank-friendly)  16640
constexpr int OFF_F3S = 16640;   // float  f3s[16][132]                            8448
// h0f (init only) overlays [0, 32768)
constexpr int OFF_RED = 32768;   // float  red[8][16][33]                         16896
constexpr int OFF_DXS = 49664;   // float  dxs[16][20]                             1280
constexpr int OFF_DTS = 50944;   // float  dts[16]                                   64
constexpr int OFF_YPK = 51008;   // ushort ypack[16][8]                             256
constexpr int OFF_B1  = 51264;   // float b1s[32]
constexpr int OFF_B2  = 51392;   // float b2s[32]
constexpr int OFF_B3  = 51520;   // float b3s[128]
constexpr int POOLSZ  = 52032;

__global__ __launch_bounds__(THREADS, 2) void cde_kernel(
    const float* __restrict__ ts,  const float* __restrict__ x,
    const float* __restrict__ Wi1, const float* __restrict__ bi1,
    const float* __restrict__ Wi2, const float* __restrict__ bi2,
    const float* __restrict__ Wf1, const float* __restrict__ bfv1,
    const float* __restrict__ Wf2, const float* __restrict__ bfv2,
    const float* __restrict__ Wf3, const float* __restrict__ bfv3,
    const float* __restrict__ Wo1, const float* __restrict__ bo1,
    const float* __restrict__ Wo2, const float* __restrict__ bo2,
    float* __restrict__ out, unsigned char* __restrict__ ws) {
  const int tid  = threadIdx.x;
  const int wave = tid >> 6;
  const int lane = tid & 63;
  const int bid  = blockIdx.x;
  const int c    = bid >> 4;   // cluster id (0..15): owns batch rows [16c, 16c+16)
  const int r    = bid & 15;   // rank in cluster: owns W cols [32r..), Wf3 cols [128r..)

  unsigned* cnt = (unsigned*)(ws + 64 * c);
  unsigned char* cbase = ws + 4096 + (size_t)c * 40960;
  unsigned short* y_buf  = (unsigned short*)(cbase);           // [16][128] bf16
  unsigned short* h1_buf = (unsigned short*)(cbase + 4096);    // [16][512] bf16
  unsigned short* h2_buf = (unsigned short*)(cbase + 20480);   // [16][512] bf16

  __shared__ __align__(16) unsigned char pool[POOLSZ];
  auto h2s = (unsigned short(*)[520])(pool + OFF_H2S);
  auto h0f = (float(*)[512])(pool);                  // init only
  auto f3s = (float(*)[132])(pool + OFF_F3S);
  auto red = (float(*)[16][33])(pool + OFF_RED);     // [8][16][33]
  float* dxs  = (float*)(pool + OFF_DXS);            // [16][20]
  float* dtsl = (float*)(pool + OFF_DTS);
  unsigned short* ypack = (unsigned short*)(pool + OFF_YPK);
  float* b1s = (float*)(pool + OFF_B1);
  float* b2s = (float*)(pool + OFF_B2);
  float* b3s = (float*)(pool + OFF_B3);
  float* gep = (float*)(pool + OFF_RED);             // epilogue scratch (16x32)

  // ---- resident weight fragments (loaded once) ----
  // P1: wave covers kt = wave>>1 (k0=32*kt), col half nt = wave&1 of our 32 cols
  bf16x8 w1f = load_bfrag(Wf1, WQ, 32 * (wave >> 1), 32 * r + 16 * (wave & 1), lane);
  bf16x8 w2f[2][2];   // P2: k in [64*wave, 64*wave+64), cols 32r+16*nt
#pragma unroll
  for (int kk = 0; kk < 2; ++kk)
#pragma unroll
    for (int nt = 0; nt < 2; ++nt)
      w2f[kk][nt] = load_bfrag(Wf2, WQ, 64 * wave + 32 * kk, 32 * r + 16 * nt, lane);
  bf16x8 w3f[16];     // P3: full K per wave, cols 128r + 16*wave
#pragma unroll
  for (int kt = 0; kt < 16; ++kt)
    w3f[kt] = load_bfrag(Wf3, HQ * IQ, 32 * kt, 128 * r + 16 * wave, lane);

  // bias slices -> LDS (persist whole kernel)
  if (tid < 32) { b1s[tid] = bfv1[32 * r + tid]; b2s[tid] = bfv2[32 * r + tid]; }
  if (tid >= 64 && tid < 192) b3s[tid - 64] = bfv3[128 * r + (tid - 64)];

  // ---- init: h0 = tanh(x0 @ Wi1 + bi1)  (16 x 512, fp32, LDS) ----
  {
    int row = tid >> 5;
    int col0 = (tid & 31) * 16;
    const float* xr = x + ((16 * c + row) * LQ) * IQ;
    float xv[16];
#pragma unroll
    for (int j = 0; j < 16; ++j) xv[j] = xr[j];
    for (int cc = 0; cc < 16; ++cc) {
      int col = col0 + cc;
      float s = bi1[col];
#pragma unroll
      for (int j = 0; j < 16; ++j) s += xv[j] * Wi1[j * WQ + col];
      h0f[row][col] = tanhf(s);
    }
  }
  __syncthreads();

  // y0 = h0 @ Wi2 + bi2 : thread t<128 owns (m = t>>3, hh = 8r + (t&7)), fp32 forever
  float y_reg = 0.f;
  const int my_m = tid >> 3, my_hl = tid & 7;
  if (tid < 128) {
    int hh = 8 * r + my_hl;
    float s = bi2[hh];
#pragma unroll 8
    for (int k = 0; k < WQ; ++k) s += h0f[my_m][k] * Wi2[k * HQ + hh];
    y_reg = s;
    ypack[my_m * 8 + my_hl] = f2bf(s);
  }
  __syncthreads();
  if (tid < 32) {
    int m = tid >> 1, hf = tid & 1;
    *(unsigned long long*)(y_buf + m * HQ + 8 * r + 4 * hf) =
        *(const unsigned long long*)(ypack + m * 8 + 4 * hf);
  }
  unsigned bk = 0;
  cluster_barrier(cnt, CBLK * (++bk));

  // ======================= main scan: 1023 steps =======================
  for (int t = 0; t < LQ - 1; ++t) {
    // ---- P1: h1 = tanh(y @ Wf1 + b1), our cols [32r, 32r+32) ----
    {
      const bf16x8 a1 = *(const bf16x8*)(y_buf + (lane & 15) * HQ +
                                         32 * (wave >> 1) + 8 * (lane >> 4));
      f32x4 acc = {0.f, 0.f, 0.f, 0.f};
      acc = MFMA16(a1, w1f, acc);
      const int colw = 16 * (wave & 1) + (lane & 15);
#pragma unroll
      for (int i = 0; i < 4; ++i) red[wave >> 1][4 * (lane >> 4) + i][colw] = acc[i];
    }
    __syncthreads();
    if (tid < 256) {
      int row = tid >> 4, cp = tid & 15;
      float v0 = b1s[2 * cp], v1 = b1s[2 * cp + 1];
#pragma unroll
      for (int s8 = 0; s8 < 4; ++s8) { v0 += red[s8][row][2 * cp]; v1 += red[s8][row][2 * cp + 1]; }
      unsigned pk = (unsigned)f2bf(tanhf(v0)) | ((unsigned)f2bf(tanhf(v1)) << 16);
      *(unsigned*)(h1_buf + row * WQ + 32 * r + 2 * cp) = pk;
    }
    cluster_barrier(cnt, CBLK * (++bk));

    // ---- P2: h2 = tanh(h1 @ Wf2 + b2), our cols [32r, 32r+32) ----
    {
      bf16x8 a2[2];
#pragma unroll
      for (int kk = 0; kk < 2; ++kk)
        a2[kk] = *(const bf16x8*)(h1_buf + (lane & 15) * WQ +
                                  64 * wave + 32 * kk + 8 * (lane >> 4));
      f32x4 acc0 = {0.f, 0.f, 0.f, 0.f}, acc1 = {0.f, 0.f, 0.f, 0.f};
#pragma unroll
      for (int kk = 0; kk < 2; ++kk) {
        acc0 = MFMA16(a2[kk], w2f[kk][0], acc0);
        acc1 = MFMA16(a2[kk], w2f[kk][1], acc1);
      }
#pragma unroll
      for (int i = 0; i < 4; ++i) {
        red[wave][4 * (lane >> 4) + i][(lane & 15)]      = acc0[i];
        red[wave][4 * (lane >> 4) + i][16 + (lane & 15)] = acc1[i];
      }
    }
    __syncthreads();
    if (tid < 256) {
      int row = tid >> 4, cp = tid & 15;
      float v0 = b2s[2 * cp], v1 = b2s[2 * cp + 1];
#pragma unroll
      for (int s8 = 0; s8 < 8; ++s8) { v0 += red[s8][row][2 * cp]; v1 += red[s8][row][2 * cp + 1]; }
      unsigned pk = (unsigned)f2bf(tanhf(v0)) | ((unsigned)f2bf(tanhf(v1)) << 16);
      *(unsigned*)(h2_buf + row * WQ + 32 * r + 2 * cp) = pk;
    }
    cluster_barrier(cnt, CBLK * (++bk));

    // ---- P3: f = h2 @ Wf3 + b3 (our 128 cols = hh in [8r,8r+8)); dy; y update ----
    {
      // stage dx, dt early (hide latency under LDS staging)
      if (tid < 256) {
        int m = tid >> 4, j = tid & 15;
        const float* xp = x + ((16 * c + m) * LQ + t) * IQ + j;
        dxs[m * 20 + j] = xp[IQ] - xp[0];
      }
      if (tid < 16) {
        const float* tp = ts + (16 * c + tid) * LQ + t;
        dtsl[tid] = tp[1] - tp[0];
      }
      // stage h2 (16KB) -> LDS once; every wave then reads full K from LDS
      {
        int row = tid >> 5, col0 = (tid & 31) * 16;
        const uint4* src = (const uint4*)(h2_buf + row * WQ + col0);
        uint4 v0 = src[0], v1 = src[1];
        uint4* dst = (uint4*)(&h2s[row][col0]);
        dst[0] = v0; dst[1] = v1;
      }
      __syncthreads();
      {
        f32x4 accA = {0.f, 0.f, 0.f, 0.f}, accB = {0.f, 0.f, 0.f, 0.f};
#pragma unroll
        for (int kt = 0; kt < 16; kt += 2) {
          const bf16x8 afA = *(const bf16x8*)(&h2s[lane & 15][32 * kt + 8 * (lane >> 4)]);
          const bf16x8 afB = *(const bf16x8*)(&h2s[lane & 15][32 * (kt + 1) + 8 * (lane >> 4)]);
          accA = MFMA16(afA, w3f[kt], accA);
          accB = MFMA16(afB, w3f[kt + 1], accB);
        }
        const int coll = 16 * wave + (lane & 15);
#pragma unroll
        for (int i = 0; i < 4; ++i)
          f3s[4 * (lane >> 4) + i][coll] = accA[i] + accB[i] + b3s[coll];
      }
      __syncthreads();
      if (tid < 128) {
        float fs = 0.f;
#pragma unroll
        for (int j = 0; j < 16; ++j)
          fs += f3s[my_m][my_hl * 16 + j] * dxs[my_m * 20 + j];
        y_reg += fs * dtsl[my_m];
        ypack[my_m * 8 + my_hl] = f2bf(y_reg);
      }
      __syncthreads();
      if (tid < 32) {
        int m = tid >> 1, hf = tid & 1;
        *(unsigned long long*)(y_buf + m * HQ + 8 * r + 4 * hf) =
            *(const unsigned long long*)(ypack + m * 8 + 4 * hf);
      }
    }
    cluster_barrier(cnt, CBLK * (++bk));
  }

  // ---- epilogue: out = sigmoid(tanh(yT @ Wo1 + bo1) @ Wo2 + bo2), block r==0 ----
  if (r == 0) {
    {
      int m = tid >> 5, o = tid & 31;
      float s = bo1[o];
#pragma unroll 8
      for (int k = 0; k < HQ; ++k) s += bf2f(y_buf[m * HQ + k]) * Wo1[k * 32 + o];
      gep[m * 32 + o] = tanhf(s);
    }
    __syncthreads();
    if (tid < 64) {
      int m = tid >> 2, oo = tid & 3;
      float s = bo2[oo];
#pragma unroll
      for (int k = 0; k < 32; ++k) s += gep[m * 32 + k] * Wo2[k * OQ + oo];
      out[(16 * c + m) * OQ + oo] = 1.f / (1.f + expf(-s));
    }
  }
}

extern "C" void kernel_launch(void* const* d_in, const int* in_sizes, int n_in,
                              void* d_out, int out_size, void* d_ws, size_t ws_size,
                              hipStream_t stream) {
  (void)in_sizes; (void)n_in; (void)out_size; (void)ws_size;
  // reset cluster barrier counters every call (ws is NOT re-poisoned between replays)
  hipMemsetAsync(d_ws, 0, 4096, stream);
  cde_kernel<<<dim3(256), dim3(THREADS), 0, stream>>>(
      (const float*)d_in[0],  (const float*)d_in[1],
      (const float*)d_in[2],  (const float*)d_in[3],
      (const float*)d_in[4],  (const float*)d_in[5],
      (const float*)d_in[6],  (const float*)d_in[7],
      (const float*)d_in[8],  (const float*)d_in[9],
      (const float*)d_in[10], (const float*)d_in[11],
      (const float*)d_in[12], (const float*)d_in[13],
      (const float*)d_in[14], (const float*)d_in[15],
      (float*)d_out, (unsigned char*)d_ws);
}

// Round 2
// 9790.577 us; speedup vs baseline: 3.1333x; 3.1333x over previous
//
#include <hip/hip_runtime.h>

// ============================================================================
// Neural CDE forward, MI355X. B=256, L=1024, I=16, H=128, W=512, O=4.
//
// 16 clusters x 16 blocks (256 blocks, 1/CU). Cluster owns 16 batch rows.
// Weights live permanently in VGPRs: Wf1 replicated per block (64 VGPR),
// Wf2/Wf3 column-sliced per block. Per step only activations move, via
// FENCE-FREE tagged-slot dataflow: 8B slots {tag|2xbf16} written/read with
// relaxed agent-scope atomics (sc-bypass to coherent L3). No fences -> no
// buffer_wbl2/buffer_inv L2 flushes (round-1's 10us/barrier killer).
// 2 exchanges per step: y -> (h1 full, h2 slice) -> h2 -> (f slice, y slice).
// ============================================================================

constexpr int LQ = 1024, IQ = 16, HQ = 128, WQ = 512, OQ = 4;
constexpr int THREADS = 512;

typedef __attribute__((ext_vector_type(8))) short bf16x8;
typedef __attribute__((ext_vector_type(4))) float f32x4;

#define MFMA16(a, b, c) __builtin_amdgcn_mfma_f32_16x16x32_bf16((a), (b), (c), 0, 0, 0)

__device__ __forceinline__ unsigned short f2bf(float f) {
  unsigned u = __builtin_bit_cast(unsigned, f);
  u += 0x7FFFu + ((u >> 16) & 1u);  // round-nearest-even
  return (unsigned short)(u >> 16);
}
__device__ __forceinline__ float bf2f(unsigned short h) {
  unsigned u = ((unsigned)h) << 16;
  return __builtin_bit_cast(float, u);
}

// B-fragment for mfma_f32_16x16x32_bf16: lane holds B[k0+8*(lane>>4)+j][n0+(lane&15)]
__device__ __forceinline__ bf16x8 load_bfrag(const float* W, int N, int k0, int n0, int lane) {
  const int col = n0 + (lane & 15);
  const int kb  = k0 + 8 * (lane >> 4);
  bf16x8 v;
#pragma unroll
  for (int j = 0; j < 8; ++j) v[j] = (short)f2bf(W[(kb + j) * N + col]);
  return v;
}

// 8B comm slot: high 32 = tag, low 32 = 2 x bf16. Relaxed agent-scope atomics
// lower to sc0/sc1 (L2-bypass) ops -> cross-XCD coherent WITHOUT fences.
__device__ __forceinline__ void slot_store(unsigned long long* p, unsigned tag, unsigned pay) {
  unsigned long long v = ((unsigned long long)tag << 32) | (unsigned long long)pay;
  __hip_atomic_store(p, v, __ATOMIC_RELAXED, __HIP_MEMORY_SCOPE_AGENT);
}
__device__ __forceinline__ unsigned long long slot_load(const unsigned long long* p) {
  return __hip_atomic_load(p, __ATOMIC_RELAXED, __HIP_MEMORY_SCOPE_AGENT);
}

// ---- LDS pool layout ----
constexpr int OFF_YS  = 0;       // bf16 y_s[16][136]                      4352
constexpr int OFF_H12 = 4352;    // bf16 [16][520]: h1s (A) / h2s (B)     16640
constexpr int OFF_RF  = 20992;   // f32 red[8][16][33] (A) / f3s[16][132] (B) / gep (epi)  16896
constexpr int OFF_B1  = 37888;   // f32 b1s[512]                           2048
constexpr int OFF_B2  = 39936;   // f32 b2s[32]                             128
constexpr int OFF_B3  = 40064;   // f32 b3s[128]                            512
constexpr int OFF_DX  = 40576;   // f32 dxs[16][20]                        1280
constexpr int OFF_DT  = 41856;   // f32 dtl[16]                              64
constexpr int OFF_YP  = 41920;   // u16 ypack[16][8]                        256
constexpr int POOLSZ  = 42240;
// h0f f32[16][512] (init only) overlays [0, 32768) -- disjoint from B1..YP.

__device__ __forceinline__ void poll_y(const unsigned long long* yslots, unsigned want,
                                       unsigned short (*y_s)[136], int tid) {
  const unsigned long long* p = yslots + 2 * tid;  // slots 2t, 2t+1 (1024 total)
  unsigned long long v0 = slot_load(p);
  unsigned long long v1 = slot_load(p + 1);
  while ((unsigned)(v0 >> 32) != want) { __builtin_amdgcn_s_sleep(1); v0 = slot_load(p); }
  while ((unsigned)(v1 >> 32) != want) { __builtin_amdgcn_s_sleep(1); v1 = slot_load(p + 1); }
  const int row = tid >> 5, c4 = (tid & 31) * 4;
  uint2 u; u.x = (unsigned)v0; u.y = (unsigned)v1;
  *(uint2*)&y_s[row][c4] = u;
}

__global__ __launch_bounds__(THREADS, 2) void cde_kernel(
    const float* __restrict__ ts,  const float* __restrict__ x,
    const float* __restrict__ Wi1, const float* __restrict__ bi1,
    const float* __restrict__ Wi2, const float* __restrict__ bi2,
    const float* __restrict__ Wf1, const float* __restrict__ bfv1,
    const float* __restrict__ Wf2, const float* __restrict__ bfv2,
    const float* __restrict__ Wf3, const float* __restrict__ bfv3,
    const float* __restrict__ Wo1, const float* __restrict__ bo1,
    const float* __restrict__ Wo2, const float* __restrict__ bo2,
    float* __restrict__ out, unsigned char* __restrict__ ws) {
  const int tid  = threadIdx.x;
  const int wave = tid >> 6;
  const int lane = tid & 63;
  const int bid  = blockIdx.x;
  const int c    = bid >> 4;   // cluster: batch rows [16c, 16c+16)
  const int r    = bid & 15;   // rank: W cols [32r..), Wf3 cols [128r..)

  unsigned long long* yslots  = (unsigned long long*)(ws + (size_t)c * 40960);          // 1024 slots
  unsigned long long* h2slots = (unsigned long long*)(ws + (size_t)c * 40960 + 8192);   // 4096 slots

  __shared__ __align__(16) unsigned char pool[POOLSZ];
  auto y_s  = (unsigned short(*)[136])(pool + OFF_YS);
  auto h1s  = (unsigned short(*)[520])(pool + OFF_H12);
  auto h2s  = (unsigned short(*)[520])(pool + OFF_H12);
  auto red  = (float(*)[16][33])(pool + OFF_RF);   // [8][16][33]
  auto f3s  = (float(*)[132])(pool + OFF_RF);
  auto h0f  = (float(*)[512])(pool);               // init only
  float* b1s = (float*)(pool + OFF_B1);
  float* b2s = (float*)(pool + OFF_B2);
  float* b3s = (float*)(pool + OFF_B3);
  float* dxs = (float*)(pool + OFF_DX);
  float* dtl = (float*)(pool + OFF_DT);
  unsigned short* ypack = (unsigned short*)(pool + OFF_YP);

  // ---- resident weight fragments ----
  bf16x8 w1f[4][4];   // Wf1 replicated: wave w owns h1 cols [64w, 64w+64)
#pragma unroll
  for (int n = 0; n < 4; ++n)
#pragma unroll
    for (int k4 = 0; k4 < 4; ++k4)
      w1f[n][k4] = load_bfrag(Wf1, WQ, 32 * k4, 64 * wave + 16 * n, lane);
  bf16x8 w2f[2][2];   // Wf2 slice: K in [64w,64w+64), cols 32r+16nt
#pragma unroll
  for (int kk = 0; kk < 2; ++kk)
#pragma unroll
    for (int nt = 0; nt < 2; ++nt)
      w2f[kk][nt] = load_bfrag(Wf2, WQ, 64 * wave + 32 * kk, 32 * r + 16 * nt, lane);
  bf16x8 w3f[16];     // Wf3 slice: full K, cols 128r + 16w
#pragma unroll
  for (int kt = 0; kt < 16; ++kt)
    w3f[kt] = load_bfrag(Wf3, HQ * IQ, 32 * kt, 128 * r + 16 * wave, lane);

  // biases
  b1s[tid] = bi1[tid];
  if (tid < 32) b2s[tid] = bfv2[32 * r + tid];
  if (tid >= 64 && tid < 192) b3s[tid - 64] = bfv3[128 * r + (tid - 64)];

  // ---- init: h0 = tanh(x0 @ Wi1 + bi1), then y0 = h0 @ Wi2 + bi2 ----
  {
    int row = tid >> 5, col0 = (tid & 31) * 16;
    const float* xr = x + ((16 * c + row) * LQ) * IQ;
    float xv[16];
#pragma unroll
    for (int j = 0; j < 16; ++j) xv[j] = xr[j];
    for (int cc = 0; cc < 16; ++cc) {
      int col = col0 + cc;
      float s = bi1[col];
#pragma unroll
      for (int j = 0; j < 16; ++j) s += xv[j] * Wi1[j * WQ + col];
      h0f[row][col] = tanhf(s);
    }
  }
  __syncthreads();
  float y_reg = 0.f;
  const int my_m = tid >> 3, my_hl = tid & 7;
  if (tid < 128) {
    int hh = 8 * r + my_hl;
    float s = bi2[hh];
#pragma unroll 8
    for (int k = 0; k < WQ; ++k) s += h0f[my_m][k] * Wi2[k * HQ + hh];
    y_reg = s;
    ypack[my_m * 8 + my_hl] = f2bf(s);
  }
  __syncthreads();
  if (tid < 64) {
    int m = tid >> 2, p4 = tid & 3;
    unsigned pay = (unsigned)ypack[m * 8 + 2 * p4] | ((unsigned)ypack[m * 8 + 2 * p4 + 1] << 16);
    slot_store(yslots + m * 64 + 4 * r + p4, 1u, pay);   // y tag for A(t) is t+1
  }

  // ======================= main scan: 1023 steps =======================
  for (int t = 0; t < LQ - 1; ++t) {
    // ---------------- phase A ----------------
    if (tid < 256) {   // stage dx (cached plain loads, overlap with poll)
      int m = tid >> 4, j = tid & 15;
      const float* xp = x + ((16 * c + m) * LQ + t) * IQ + j;
      dxs[m * 20 + j] = xp[IQ] - xp[0];
    }
    if (tid < 16) {
      const float* tp = ts + (16 * c + tid) * LQ + t;
      dtl[tid] = tp[1] - tp[0];
    }
    poll_y(yslots, (unsigned)(t + 1), y_s, tid);
    __syncthreads();
    // h1 = tanh(y @ Wf1 + b1) : full 512 cols, wave w -> cols [64w, 64w+64)
    {
      bf16x8 af[4];
#pragma unroll
      for (int k4 = 0; k4 < 4; ++k4)
        af[k4] = *(const bf16x8*)&y_s[lane & 15][32 * k4 + 8 * (lane >> 4)];
#pragma unroll
      for (int n = 0; n < 4; ++n) {
        f32x4 acc = {0.f, 0.f, 0.f, 0.f};
#pragma unroll
        for (int k4 = 0; k4 < 4; ++k4) acc = MFMA16(af[k4], w1f[n][k4], acc);
        const int col = 64 * wave + 16 * n + (lane & 15);
        const float bb = b1s[col];
#pragma unroll
        for (int i = 0; i < 4; ++i)
          h1s[4 * (lane >> 4) + i][col] = f2bf(tanhf(acc[i] + bb));
      }
    }
    __syncthreads();
    // h2 slice = tanh(h1 @ Wf2 + b2)[:, 32r:32r+32], K split across waves
    {
      f32x4 acc0 = {0.f, 0.f, 0.f, 0.f}, acc1 = {0.f, 0.f, 0.f, 0.f};
#pragma unroll
      for (int kk = 0; kk < 2; ++kk) {
        const bf16x8 a2 = *(const bf16x8*)&h1s[lane & 15][64 * wave + 32 * kk + 8 * (lane >> 4)];
        acc0 = MFMA16(a2, w2f[kk][0], acc0);
        acc1 = MFMA16(a2, w2f[kk][1], acc1);
      }
#pragma unroll
      for (int i = 0; i < 4; ++i) {
        red[wave][4 * (lane >> 4) + i][lane & 15]        = acc0[i];
        red[wave][4 * (lane >> 4) + i][16 + (lane & 15)] = acc1[i];
      }
    }
    __syncthreads();
    if (tid < 256) {  // reduce 8 partials, tanh, publish h2 slice (tagged)
      int row = tid >> 4, cp = tid & 15;
      float v0 = b2s[2 * cp], v1 = b2s[2 * cp + 1];
#pragma unroll
      for (int s8 = 0; s8 < 8; ++s8) { v0 += red[s8][row][2 * cp]; v1 += red[s8][row][2 * cp + 1]; }
      unsigned pk = (unsigned)f2bf(tanhf(v0)) | ((unsigned)f2bf(tanhf(v1)) << 16);
      slot_store(h2slots + row * 256 + 16 * r + cp, 2048u + (unsigned)t, pk);
    }
    // ---------------- phase B ----------------
    {  // poll full h2 (4096 slots; 8 per thread) -> LDS
      const unsigned long long* p = h2slots + 8 * tid;
      unsigned long long v[8];
#pragma unroll
      for (int j = 0; j < 8; ++j) v[j] = slot_load(p + j);
      const unsigned want = 2048u + (unsigned)t;
      while (true) {
        bool ok = true;
#pragma unroll
        for (int j = 0; j < 8; ++j) ok &= ((unsigned)(v[j] >> 32) == want);
        if (ok) break;
        __builtin_amdgcn_s_sleep(1);
#pragma unroll
        for (int j = 0; j < 8; ++j)
          if ((unsigned)(v[j] >> 32) != want) v[j] = slot_load(p + j);
      }
      const int row = tid >> 5, c16 = (tid & 31) * 16;
      unsigned d[8];
#pragma unroll
      for (int j = 0; j < 8; ++j) d[j] = (unsigned)v[j];
      *(uint4*)&h2s[row][c16]     = *(const uint4*)&d[0];
      *(uint4*)&h2s[row][c16 + 8] = *(const uint4*)&d[4];
    }
    __syncthreads();
    // f slice = h2 @ Wf3 + b3 : our 128 cols, wave w -> cols [16w,16w+16)
    {
      f32x4 accA = {0.f, 0.f, 0.f, 0.f}, accB = {0.f, 0.f, 0.f, 0.f};
#pragma unroll
      for (int kt = 0; kt < 16; kt += 2) {
        const bf16x8 aA = *(const bf16x8*)&h2s[lane & 15][32 * kt + 8 * (lane >> 4)];
        const bf16x8 aB = *(const bf16x8*)&h2s[lane & 15][32 * (kt + 1) + 8 * (lane >> 4)];
        accA = MFMA16(aA, w3f[kt], accA);
        accB = MFMA16(aB, w3f[kt + 1], accB);
      }
      const int coll = 16 * wave + (lane & 15);
#pragma unroll
      for (int i = 0; i < 4; ++i)
        f3s[4 * (lane >> 4) + i][coll] = accA[i] + accB[i] + b3s[coll];
    }
    __syncthreads();
    if (tid < 128) {  // dy, fp32 y update
      float fs = 0.f;
#pragma unroll
      for (int j = 0; j < 16; ++j) fs += f3s[my_m][my_hl * 16 + j] * dxs[my_m * 20 + j];
      y_reg += fs * dtl[my_m];
      ypack[my_m * 8 + my_hl] = f2bf(y_reg);
    }
    __syncthreads();
    if (tid < 64) {   // publish y slice, tag t+2
      int m = tid >> 2, p4 = tid & 3;
      unsigned pay = (unsigned)ypack[m * 8 + 2 * p4] | ((unsigned)ypack[m * 8 + 2 * p4 + 1] << 16);
      slot_store(yslots + m * 64 + 4 * r + p4, (unsigned)(t + 2), pay);
    }
  }

  // ---- epilogue: out = sigmoid(tanh(yT @ Wo1 + bo1) @ Wo2 + bo2) ----
  if (r == 0) {
    poll_y(yslots, (unsigned)LQ, y_s, tid);   // tag 1024 = final y
    __syncthreads();
    float* gep = (float*)(pool + OFF_RF);
    {
      int m = tid >> 5, o = tid & 31;
      float s = bo1[o];
#pragma unroll 8
      for (int k = 0; k < HQ; ++k) s += bf2f(y_s[m][k]) * Wo1[k * 32 + o];
      gep[m * 32 + o] = tanhf(s);
    }
    __syncthreads();
    if (tid < 64) {
      int m = tid >> 2, oo = tid & 3;
      float s = bo2[oo];
#pragma unroll
      for (int k = 0; k < 32; ++k) s += gep[m * 32 + k] * Wo2[k * OQ + oo];
      out[(16 * c + m) * OQ + oo] = 1.f / (1.f + expf(-s));
    }
  }
}

extern "C" void kernel_launch(void* const* d_in, const int* in_sizes, int n_in,
                              void* d_out, int out_size, void* d_ws, size_t ws_size,
                              hipStream_t stream) {
  (void)in_sizes; (void)n_in; (void)out_size; (void)ws_size;
  // clear all slot tags every call (stale tags from prior replay / poison)
  hipMemsetAsync(d_ws, 0, 16 * 40960, stream);
  cde_kernel<<<dim3(256), dim3(THREADS), 0, stream>>>(
      (const float*)d_in[0],  (const float*)d_in[1],
      (const float*)d_in[2],  (const float*)d_in[3],
      (const float*)d_in[4],  (const float*)d_in[5],
      (const float*)d_in[6],  (const float*)d_in[7],
      (const float*)d_in[8],  (const float*)d_in[9],
      (const float*)d_in[10], (const float*)d_in[11],
      (const float*)d_in[12], (const float*)d_in[13],
      (const float*)d_in[14], (const float*)d_in[15],
      (float*)d_out, (unsigned char*)d_ws);
}

// Round 4
// 7121.042 us; speedup vs baseline: 4.3079x; 1.3749x over previous
//
#include <hip/hip_runtime.h>

// ============================================================================
// Neural CDE forward, MI355X. B=256, L=1024, I=16, H=128, W=512, O=4.
//
// 16 clusters x 16 blocks (256 blocks = 256 CUs, co-resident). Cluster owns 16
// batch rows; recurrence runs fully on-chip. Weights permanently in VGPRs
// (Wf1 replicated, Wf2/Wf3 column-sliced) -> zero per-step weight traffic.
//
// Comm primitive (PROVEN in round 2): __hip_atomic_* RELAXED AGENT scope
// (cross-XCD coherent, no fences -> no buffer_wbl2/inv L2 flushes).
// Protocol (round-3 design): producer payload stores -> waitcnt+barrier ->
// ONE 4B flag store; consumer polls ONE flag (16 flags = 1 cacheline/wave),
// then one vectorized payload read. Parity double-buffering -> race-free.
// ============================================================================

constexpr int LQ = 1024, IQ = 16, HQ = 128, WQ = 512, OQ = 4;
constexpr int THREADS = 512;
constexpr size_t CSTRIDE = 49152;

typedef __attribute__((ext_vector_type(8))) short bf16x8;
typedef __attribute__((ext_vector_type(4))) float f32x4;
typedef unsigned int u32t;
typedef unsigned long long u64t;

#define MFMA16(a, b, c) __builtin_amdgcn_mfma_f32_16x16x32_bf16((a), (b), (c), 0, 0, 0)

__device__ __forceinline__ unsigned short f2bf(float f) {
  unsigned u = __builtin_bit_cast(unsigned, f);
  u += 0x7FFFu + ((u >> 16) & 1u);  // round-nearest-even
  return (unsigned short)(u >> 16);
}
__device__ __forceinline__ float bf2f(unsigned short h) {
  unsigned u = ((unsigned)h) << 16;
  return __builtin_bit_cast(float, u);
}
__device__ __forceinline__ float fast_tanh(float x) {
  float e = __expf(2.0f * x);       // exact at saturation: +/-1
  return 1.0f - 2.0f / (e + 1.0f);
}

// B-fragment for mfma_f32_16x16x32_bf16: lane holds B[k0+8*(lane>>4)+j][n0+(lane&15)]
__device__ __forceinline__ bf16x8 load_bfrag(const float* W, int N, int k0, int n0, int lane) {
  const int col = n0 + (lane & 15);
  const int kb  = k0 + 8 * (lane >> 4);
  bf16x8 v;
#pragma unroll
  for (int j = 0; j < 8; ++j) v[j] = (short)f2bf(W[(kb + j) * N + col]);
  return v;
}

// ---- proven comm primitives: relaxed agent-scope atomics ----
__device__ __forceinline__ void st32a(u32t* p, u32t v) {
  __hip_atomic_store(p, v, __ATOMIC_RELAXED, __HIP_MEMORY_SCOPE_AGENT);
}
__device__ __forceinline__ u32t ld32a(const u32t* p) {
  return __hip_atomic_load(p, __ATOMIC_RELAXED, __HIP_MEMORY_SCOPE_AGENT);
}
__device__ __forceinline__ void st64a(u64t* p, u64t v) {
  __hip_atomic_store(p, v, __ATOMIC_RELAXED, __HIP_MEMORY_SCOPE_AGENT);
}
__device__ __forceinline__ u64t ld64a(const u64t* p) {
  return __hip_atomic_load(p, __ATOMIC_RELAXED, __HIP_MEMORY_SCOPE_AGENT);
}
__device__ __forceinline__ void pollf(const u32t* p, u32t want) {
  while (ld32a(p) != want) __builtin_amdgcn_s_sleep(2);
  asm volatile("" ::: "memory");  // keep payload loads below the poll
}
__device__ __forceinline__ void drain_all() { __builtin_amdgcn_s_waitcnt(0); }

// ---- LDS pool layout ----
constexpr int OFF_YS  = 0;       // u16 y_s[16][136]                      4352
constexpr int OFF_H12 = 4352;    // u16 [16][520]: h1s / h2s             16640
constexpr int OFF_RED = 20992;   // f32 red[8][16][33] / gep (epilogue)  16896
constexpr int OFF_B1  = 37888;   // f32 b1s[512]
constexpr int OFF_B2  = 39936;   // f32 b2s[32]
constexpr int OFF_B3  = 40064;   // f32 b3s[128]
constexpr int OFF_DX  = 40576;   // f32 dxs[16][20]  (y0f[128] overlays, init only)
constexpr int OFF_DT  = 41856;   // f32 dtl[16]
constexpr int OFF_YP  = 41920;   // u16 ypack[16][8]
constexpr int POOLSZ  = 42176;
// h0f f32[16][512] (init only) overlays [0, 32768).

__global__ __launch_bounds__(THREADS, 2) void cde_kernel(
    const float* __restrict__ ts,  const float* __restrict__ x,
    const float* __restrict__ Wi1, const float* __restrict__ bi1,
    const float* __restrict__ Wi2, const float* __restrict__ bi2,
    const float* __restrict__ Wf1, const float* __restrict__ bfv1,
    const float* __restrict__ Wf2, const float* __restrict__ bfv2,
    const float* __restrict__ Wf3, const float* __restrict__ bfv3,
    const float* __restrict__ Wo1, const float* __restrict__ bo1,
    const float* __restrict__ Wo2, const float* __restrict__ bo2,
    float* __restrict__ out, unsigned char* __restrict__ ws) {
  const int tid  = threadIdx.x;
  const int wave = tid >> 6;
  const int lane = tid & 63;
  const int bid  = blockIdx.x;
  const int c    = bid >> 4;   // cluster: batch rows [16c, 16c+16)
  const int r    = bid & 15;   // rank: Wf2 cols [32r..), Wf3 cols [128r..)

  unsigned char* cb = ws + (size_t)c * CSTRIDE;
  u32t* fy = (u32t*)cb;                                  // [2][32] parity flags, y
  u32t* fh = (u32t*)(cb + 256);                          // [2][32] parity flags, h2
  unsigned short* ybuf  = (unsigned short*)(cb + 512);   // [2][16][128] bf16
  unsigned short* h2buf = (unsigned short*)(cb + 8704);  // [2][16][512] bf16

  __shared__ __align__(16) unsigned char pool[POOLSZ];
  auto y_s = (unsigned short(*)[136])(pool + OFF_YS);
  auto h1s = (unsigned short(*)[520])(pool + OFF_H12);
  auto h2s = (unsigned short(*)[520])(pool + OFF_H12);
  auto red = (float(*)[16][33])(pool + OFF_RED);
  auto h0f = (float(*)[512])(pool);                      // init only
  float* b1s = (float*)(pool + OFF_B1);
  float* b2s = (float*)(pool + OFF_B2);
  float* b3s = (float*)(pool + OFF_B3);
  float* dxs = (float*)(pool + OFF_DX);
  float* y0f = (float*)(pool + OFF_DX);                  // init only overlay
  float* dtl = (float*)(pool + OFF_DT);
  unsigned short* ypack = (unsigned short*)(pool + OFF_YP);

  // ---- resident weight fragments ----
  bf16x8 w1f[4][4];   // Wf1 replicated: wave w -> h1 cols [64w, 64w+64)
#pragma unroll
  for (int n = 0; n < 4; ++n)
#pragma unroll
    for (int k4 = 0; k4 < 4; ++k4)
      w1f[n][k4] = load_bfrag(Wf1, WQ, 32 * k4, 64 * wave + 16 * n, lane);
  const int w_nt = wave & 1, w_q = wave >> 1;
  bf16x8 w2f[4];      // Wf2 slice: n-half w_nt of our 32 cols, K-quarter w_q
#pragma unroll
  for (int kk = 0; kk < 4; ++kk)
    w2f[kk] = load_bfrag(Wf2, WQ, 32 * (4 * w_q + kk), 32 * r + 16 * w_nt, lane);
  bf16x8 w3f[16];     // Wf3 slice: full K, cols 128r + 16w  (h = 8r + w, all i)
#pragma unroll
  for (int kt = 0; kt < 16; ++kt)
    w3f[kt] = load_bfrag(Wf3, HQ * IQ, 32 * kt, 128 * r + 16 * wave, lane);

  b1s[tid] = bi1[tid];
  if (tid < 32) b2s[tid] = bfv2[32 * r + tid];
  if (tid >= 64 && tid < 192) b3s[tid - 64] = bfv3[128 * r + (tid - 64)];

  // ---- init: h0 = tanh(x0 @ Wi1 + bi1); y0 = h0 @ Wi2 + bi2 (fp32) ----
  {
    int row = tid >> 5, col0 = (tid & 31) * 16;
    const float* xr = x + ((16 * c + row) * LQ) * IQ;
    float xv[16];
#pragma unroll
    for (int j = 0; j < 16; ++j) xv[j] = xr[j];
    for (int cc = 0; cc < 16; ++cc) {
      int col = col0 + cc;
      float s = bi1[col];
#pragma unroll
      for (int j = 0; j < 16; ++j) s += xv[j] * Wi1[j * WQ + col];
      h0f[row][col] = tanhf(s);
    }
  }
  __syncthreads();
  if (tid < 128) {
    int m = tid >> 3, hl = tid & 7, hh = 8 * r + hl;
    float s = bi2[hh];
#pragma unroll 8
    for (int k = 0; k < WQ; ++k) s += h0f[m][k] * Wi2[k * HQ + hh];
    ypack[m * 8 + hl] = f2bf(s);
    y0f[m * 8 + hl] = s;
  }
  __syncthreads();
  // per-lane fp32 y state: rows 4*(lane>>4)+i, col h = 8r + wave (16 replicas)
  f32x4 y4;
  {
    const int q4 = 4 * (lane >> 4);
#pragma unroll
    for (int i = 0; i < 4; ++i) y4[i] = y0f[(q4 + i) * 8 + wave];
  }
  if (tid < 32) {   // publish y0 into parity 0 (tag 1)
    int m = tid >> 1, hf = tid & 1;
    u64t v = *(const u64t*)&ypack[m * 8 + 4 * hf];
    st64a((u64t*)(ybuf + m * HQ + 8 * r + 4 * hf), v);
  }
  drain_all();
  __syncthreads();
  if (tid == 0) st32a(fy + 0 * 32 + r, 1u);

  const int g_row = tid >> 5, g_pr = (tid & 31) >> 1;
  const int g_c4 = (tid & 31) * 4, g_c16 = (tid & 31) * 16;

  // ======================= main scan: 1023 steps =======================
  for (int t = 0; t < LQ - 1; ++t) {
    const int par = t & 1, pn = par ^ 1;
    // stage dx/dt (plain cached loads)
    if (tid < 256) {
      int m = tid >> 4, j = tid & 15;
      const float* xp = x + ((16 * c + m) * LQ + t) * IQ + j;
      dxs[m * 20 + j] = xp[IQ] - xp[0];
    }
    if (tid < 16) {
      const float* tp = ts + (16 * c + tid) * LQ + t;
      dtl[tid] = tp[1] - tp[0];
    }
    // ---- y gather: one flag poll + one 8B read per thread ----
    pollf(fy + par * 32 + g_pr, (u32t)(t + 1));
    {
      u64t v = ld64a((const u64t*)(ybuf + par * 2048 + g_row * HQ + g_c4));
      *(u64t*)&y_s[g_row][g_c4] = v;
    }
    __syncthreads();                                       // B1
    // ---- P1: h1 = tanh(y @ Wf1 + b1), wave w -> cols [64w, 64w+64) ----
    {
      bf16x8 af[4];
#pragma unroll
      for (int k4 = 0; k4 < 4; ++k4)
        af[k4] = *(const bf16x8*)&y_s[lane & 15][32 * k4 + 8 * (lane >> 4)];
#pragma unroll
      for (int n = 0; n < 4; ++n) {
        f32x4 acc = {0.f, 0.f, 0.f, 0.f};
#pragma unroll
        for (int k4 = 0; k4 < 4; ++k4) acc = MFMA16(af[k4], w1f[n][k4], acc);
        const int col = 64 * wave + 16 * n + (lane & 15);
        const float bb = b1s[col];
#pragma unroll
        for (int i = 0; i < 4; ++i)
          h1s[4 * (lane >> 4) + i][col] = f2bf(fast_tanh(acc[i] + bb));
      }
    }
    __syncthreads();                                       // B2
    // ---- P2: h2 partials, wave -> (n-half w_nt, K-quarter w_q) ----
    {
      f32x4 a0 = {0.f, 0.f, 0.f, 0.f}, a1 = {0.f, 0.f, 0.f, 0.f};
#pragma unroll
      for (int kk = 0; kk < 2; ++kk) {
        const bf16x8 f0 = *(const bf16x8*)&h1s[lane & 15][32 * (4 * w_q + kk) + 8 * (lane >> 4)];
        const bf16x8 f1 = *(const bf16x8*)&h1s[lane & 15][32 * (4 * w_q + kk + 2) + 8 * (lane >> 4)];
        a0 = MFMA16(f0, w2f[kk], a0);
        a1 = MFMA16(f1, w2f[kk + 2], a1);
      }
#pragma unroll
      for (int i = 0; i < 4; ++i)
        red[wave][4 * (lane >> 4) + i][lane & 15] = a0[i] + a1[i];
    }
    __syncthreads();                                       // B3
    if (tid < 256) {  // reduce 4 K-partials + bias + tanh, publish h2 slice
      int row = tid >> 4, cp = tid & 15;
      int c0 = 2 * cp, c1 = c0 + 1, nt = cp >> 3, l0 = c0 & 15, l1 = c1 & 15;
      float v0 = b2s[c0], v1 = b2s[c1];
#pragma unroll
      for (int q = 0; q < 4; ++q) {
        v0 += red[(q << 1) | nt][row][l0];
        v1 += red[(q << 1) | nt][row][l1];
      }
      u32t pk = (u32t)f2bf(fast_tanh(v0)) | ((u32t)f2bf(fast_tanh(v1)) << 16);
      st32a((u32t*)(h2buf + par * 8192 + row * WQ + 32 * r + c0), pk);
    }
    drain_all();
    __syncthreads();                                       // B4
    if (tid == 0) st32a(fh + par * 32 + r, (u32t)(t + 1));
    // ---- h2 gather: one flag poll + 32B read per thread ----
    pollf(fh + par * 32 + g_pr, (u32t)(t + 1));
    {
      const u64t* p = (const u64t*)(h2buf + par * 8192 + g_row * WQ + g_c16);
      u64t v0 = ld64a(p), v1 = ld64a(p + 1), v2 = ld64a(p + 2), v3 = ld64a(p + 3);
      u64t* d = (u64t*)&h2s[g_row][g_c16];
      d[0] = v0; d[1] = v1; d[2] = v2; d[3] = v3;
    }
    __syncthreads();                                       // B5
    // ---- P3: f(:, h=8r+w, :) = h2 @ Wf3 + b3; dy in-wave; y update ----
    {
      f32x4 ac0 = {0.f, 0.f, 0.f, 0.f}, ac1 = {0.f, 0.f, 0.f, 0.f};
      f32x4 ac2 = {0.f, 0.f, 0.f, 0.f}, ac3 = {0.f, 0.f, 0.f, 0.f};
#pragma unroll
      for (int kt = 0; kt < 16; kt += 4) {
        const bf16x8 a0 = *(const bf16x8*)&h2s[lane & 15][32 * kt + 8 * (lane >> 4)];
        const bf16x8 a1 = *(const bf16x8*)&h2s[lane & 15][32 * (kt + 1) + 8 * (lane >> 4)];
        const bf16x8 a2 = *(const bf16x8*)&h2s[lane & 15][32 * (kt + 2) + 8 * (lane >> 4)];
        const bf16x8 a3 = *(const bf16x8*)&h2s[lane & 15][32 * (kt + 3) + 8 * (lane >> 4)];
        ac0 = MFMA16(a0, w3f[kt], ac0);
        ac1 = MFMA16(a1, w3f[kt + 1], ac1);
        ac2 = MFMA16(a2, w3f[kt + 2], ac2);
        ac3 = MFMA16(a3, w3f[kt + 3], ac3);
      }
      const float bb = b3s[16 * wave + (lane & 15)];
      const int q4 = 4 * (lane >> 4);
      f32x4 p;
#pragma unroll
      for (int i = 0; i < 4; ++i)
        p[i] = (ac0[i] + ac1[i] + ac2[i] + ac3[i] + bb) * dxs[(q4 + i) * 20 + (lane & 15)];
      // butterfly sum over i-index (lane&15): all 16 lanes get the total
#pragma unroll
      for (int m = 1; m <= 8; m <<= 1) {
#pragma unroll
        for (int i = 0; i < 4; ++i) p[i] += __shfl_xor(p[i], m, 64);
      }
#pragma unroll
      for (int i = 0; i < 4; ++i) y4[i] += p[i] * dtl[q4 + i];
      if ((lane & 15) == 0) {
#pragma unroll
        for (int i = 0; i < 4; ++i) ypack[(q4 + i) * 8 + wave] = f2bf(y4[i]);
      }
    }
    __syncthreads();                                       // B6
    if (tid < 32) {   // publish y slice into the OTHER parity buffer
      int m = tid >> 1, hf = tid & 1;
      u64t v = *(const u64t*)&ypack[m * 8 + 4 * hf];
      st64a((u64t*)(ybuf + pn * 2048 + m * HQ + 8 * r + 4 * hf), v);
    }
    drain_all();
    __syncthreads();                                       // B7
    if (tid == 0) st32a(fy + pn * 32 + r, (u32t)(t + 2));
  }

  // ---- epilogue: out = sigmoid(tanh(yT @ Wo1 + bo1) @ Wo2 + bo2) ----
  if (r == 0) {
    pollf(fy + 1 * 32 + g_pr, (u32t)LQ);   // final y: tag 1024, parity 1
    {
      u64t v = ld64a((const u64t*)(ybuf + 2048 + g_row * HQ + g_c4));
      *(u64t*)&y_s[g_row][g_c4] = v;
    }
    __syncthreads();
    float* gep = (float*)(pool + OFF_RED);
    {
      int m = tid >> 5, o = tid & 31;
      float s = bo1[o];
#pragma unroll 8
      for (int k = 0; k < HQ; ++k) s += bf2f(y_s[m][k]) * Wo1[k * 32 + o];
      gep[m * 32 + o] = tanhf(s);
    }
    __syncthreads();
    if (tid < 64) {
      int m = tid >> 2, oo = tid & 3;
      float s = bo2[oo];
#pragma unroll
      for (int k = 0; k < 32; ++k) s += gep[m * 32 + k] * Wo2[k * OQ + oo];
      out[(16 * c + m) * OQ + oo] = 1.f / (1.f + __expf(-s));
    }
  }
}

extern "C" void kernel_launch(void* const* d_in, const int* in_sizes, int n_in,
                              void* d_out, int out_size, void* d_ws, size_t ws_size,
                              hipStream_t stream) {
  (void)in_sizes; (void)n_in; (void)out_size; (void)ws_size;
  // clear all flags/payloads every call (ws is not re-poisoned between replays)
  hipMemsetAsync(d_ws, 0, 16 * CSTRIDE, stream);
  cde_kernel<<<dim3(256), dim3(THREADS), 0, stream>>>(
      (const float*)d_in[0],  (const float*)d_in[1],
      (const float*)d_in[2],  (const float*)d_in[3],
      (const float*)d_in[4],  (const float*)d_in[5],
      (const float*)d_in[6],  (const float*)d_in[7],
      (const float*)d_in[8],  (const float*)d_in[9],
      (const float*)d_in[10], (const float*)d_in[11],
      (const float*)d_in[12], (const float*)d_in[13],
      (const float*)d_in[14], (const float*)d_in[15],
      (float*)d_out, (unsigned char*)d_ws);
}

// Round 5
// 6569.968 us; speedup vs baseline: 4.6693x; 1.0839x over previous
//
#include <hip/hip_runtime.h>

// ============================================================================
// Neural CDE forward, MI355X. B=256, L=1024, I=16, H=128, W=512, O=4.
//
// 16 clusters x 16 blocks. Cluster owns 16 batch rows. Weights in VGPRs:
// Wf1 replicated, Wf2 column-sliced, Wf3 K-SLICED (rows [32r,32r+32) x 2048).
// y state: FULL 16x128 fp32, replicated in every block's registers.
//
// ONE exchange per step: partial dy (16x128 fp32) combined across the 16
// blocks via global_atomic_add_f32 (relaxed, agent scope) into a 4-deep
// rotating buffer; completion via one monotone counter per buffer. Buffer
// zeroing is race-free by the dependency chain (buf t&3 is zeroed at step
// t-2, provably after all step-(t-4) readers and before all step-t writers).
//
// P3 trick: dy[b,h] = sum_{k,j} (h2[b,k]*dx[b,j]) * Wf3[32r+k, 16h+j] is ONE
// MFMA chain with K'=(k,j)=512: A' built in-register (v_cvt_pk_bf16_f32),
// B' fragments precomputed at init. Bias folded in as an extra K=32 MFMA
// (A''=dx, B''=bfv3), executed by block r==0 only. No shuffles, no butterfly.
// ============================================================================

constexpr int LQ = 1024, IQ = 16, HQ = 128, WQ = 512, OQ = 4;
constexpr int THREADS = 512;
constexpr size_t CSTRIDE = 49152;

typedef __attribute__((ext_vector_type(8))) short bf16x8;
typedef __attribute__((ext_vector_type(4))) float f32x4;
typedef unsigned int u32t;
typedef unsigned long long u64t;

#define MFMA16(a, b, c) __builtin_amdgcn_mfma_f32_16x16x32_bf16((a), (b), (c), 0, 0, 0)

__device__ __forceinline__ unsigned short f2bf(float f) {
  unsigned u = __builtin_bit_cast(unsigned, f);
  u += 0x7FFFu + ((u >> 16) & 1u);  // RNE
  return (unsigned short)(u >> 16);
}
__device__ __forceinline__ float bf2f(unsigned short h) {
  unsigned u = ((unsigned)h) << 16;
  return __builtin_bit_cast(float, u);
}
__device__ __forceinline__ float fast_tanh(float x) {
  float e = __expf(2.0f * x);
  return 1.0f - 2.0f / (e + 1.0f);
}
__device__ __forceinline__ u32t cvtpk(float lo, float hi) {
  u32t r;
  asm("v_cvt_pk_bf16_f32 %0, %1, %2" : "=v"(r) : "v"(lo), "v"(hi));
  return r;
}

// B-fragment: lane holds B[k0+8*(lane>>4)+j][n0+(lane&15)]
__device__ __forceinline__ bf16x8 load_bfrag(const float* W, int N, int k0, int n0, int lane) {
  const int col = n0 + (lane & 15);
  const int kb  = k0 + 8 * (lane >> 4);
  bf16x8 v;
#pragma unroll
  for (int j = 0; j < 8; ++j) v[j] = (short)f2bf(W[(kb + j) * N + col]);
  return v;
}

// ---- proven comm primitives: relaxed agent-scope atomics ----
__device__ __forceinline__ void st32a(u32t* p, u32t v) {
  __hip_atomic_store(p, v, __ATOMIC_RELAXED, __HIP_MEMORY_SCOPE_AGENT);
}
__device__ __forceinline__ u32t ld32a(const u32t* p) {
  return __hip_atomic_load(p, __ATOMIC_RELAXED, __HIP_MEMORY_SCOPE_AGENT);
}
__device__ __forceinline__ void st64a(u64t* p, u64t v) {
  __hip_atomic_store(p, v, __ATOMIC_RELAXED, __HIP_MEMORY_SCOPE_AGENT);
}
__device__ __forceinline__ u64t ld64a(const u64t* p) {
  return __hip_atomic_load(p, __ATOMIC_RELAXED, __HIP_MEMORY_SCOPE_AGENT);
}
__device__ __forceinline__ void faddA(float* p, float v) {
  __hip_atomic_fetch_add(p, v, __ATOMIC_RELAXED, __HIP_MEMORY_SCOPE_AGENT);
}
__device__ __forceinline__ void pollge(const u32t* p, u32t want) {
  while (ld32a(p) < want) __builtin_amdgcn_s_sleep(2);
  asm volatile("" ::: "memory");
}
__device__ __forceinline__ void drain_all() { __builtin_amdgcn_s_waitcnt(0); }

// ---- LDS pool layout ----
constexpr int OFF_YS  = 0;       // u16 y_s[16][136]          4352   (epi: gep f32[16][32])
constexpr int OFF_H1  = 4352;    // u16 h1s[16][520]         16640
constexpr int OFF_RED = 20992;   // f32 red[8][16][33]       16896   (epi: yf f32[16][128])
constexpr int OFF_B1  = 37888;   // f32 b1s[512]              2048
constexpr int OFF_B2  = 39936;   // f32 b2s[32]                128
constexpr int OFF_H2S = 40064;   // u16 h2s[16][40]           1280
constexpr int OFF_DX  = 41344;   // f32 dxs[16][20]           1280
constexpr int OFF_DT  = 42624;   // f32 dtl[16]                 64
constexpr int POOLSZ  = 42688;
// h0f f32[16][512] (init only) overlays [0, 32768).

// ---- ws layout per cluster (cb) ----
// +0,128,256,384 : u32 cnt[4] (one per rotating dy buffer, own cachelines)
// +512           : f32 dy[4][16*128]  (32 KB)
// +33280         : f32 y0buf[16*128]  (8 KB, init broadcast)
// +41472         : u32 fy[16]         (init flags)

__global__ __launch_bounds__(THREADS, 2) void cde_kernel(
    const float* __restrict__ ts,  const float* __restrict__ x,
    const float* __restrict__ Wi1, const float* __restrict__ bi1,
    const float* __restrict__ Wi2, const float* __restrict__ bi2,
    const float* __restrict__ Wf1, const float* __restrict__ bfv1,
    const float* __restrict__ Wf2, const float* __restrict__ bfv2,
    const float* __restrict__ Wf3, const float* __restrict__ bfv3,
    const float* __restrict__ Wo1, const float* __restrict__ bo1,
    const float* __restrict__ Wo2, const float* __restrict__ bo2,
    float* __restrict__ out, unsigned char* __restrict__ ws) {
  const int tid  = threadIdx.x;
  const int wave = tid >> 6;
  const int lane = tid & 63;
  const int bid  = blockIdx.x;
  const int c    = bid >> 4;   // cluster: batch rows [16c, 16c+16)
  const int r    = bid & 15;   // rank: Wf2 cols [32r..), Wf3 rows [32r..)

  unsigned char* cb = ws + (size_t)c * CSTRIDE;
  float* dyb  = (float*)(cb + 512);
  float* y0b  = (float*)(cb + 33280);
  u32t*  fy   = (u32t*)(cb + 41472);

  __shared__ __align__(16) unsigned char pool[POOLSZ];
  auto y_s = (unsigned short(*)[136])(pool + OFF_YS);
  auto h1s = (unsigned short(*)[520])(pool + OFF_H1);
  auto red = (float(*)[16][33])(pool + OFF_RED);
  auto h2s = (unsigned short(*)[40])(pool + OFF_H2S);
  auto h0f = (float(*)[512])(pool);                 // init only
  float* b1s = (float*)(pool + OFF_B1);
  float* b2s = (float*)(pool + OFF_B2);
  float* dxs = (float*)(pool + OFF_DX);
  float* dtl = (float*)(pool + OFF_DT);

  // ---- resident weight fragments ----
  bf16x8 w1f[4][4];   // Wf1 replicated: wave w -> h1 cols [64w, 64w+64)
#pragma unroll
  for (int n = 0; n < 4; ++n)
#pragma unroll
    for (int k4 = 0; k4 < 4; ++k4)
      w1f[n][k4] = load_bfrag(Wf1, WQ, 32 * k4, 64 * wave + 16 * n, lane);
  const int w_nt = wave & 1, w_q = wave >> 1;
  bf16x8 w2f[4];      // Wf2 slice: n-half w_nt of cols [32r,32r+32), K-quarter w_q
#pragma unroll
  for (int kk = 0; kk < 4; ++kk)
    w2f[kk] = load_bfrag(Wf2, WQ, 32 * (4 * w_q + kk), 32 * r + 16 * w_nt, lane);
  // Wf3 as B'[(k,j)][h]: B'[16k+j][h] = Wf3[32r+k][16h+j]; wave w -> h tile [16w,16w+16)
  bf16x8 w3f[16];
  {
    const int h = 16 * wave + (lane & 15);
#pragma unroll
    for (int kk = 0; kk < 16; ++kk) {
      bf16x8 v;
#pragma unroll
      for (int jj = 0; jj < 8; ++jj) {
        int Kp = 32 * kk + 8 * (lane >> 4) + jj;
        int k = Kp >> 4, j = Kp & 15;
        v[jj] = (short)f2bf(Wf3[(32 * r + k) * (HQ * IQ) + 16 * h + j]);
      }
      w3f[kk] = v;
    }
  }
  bf16x8 w3b;  // bias frag: B''[K''][h] = (K''<16) ? bfv3[16h+K''] : 0
  {
    const int h = 16 * wave + (lane & 15);
    bf16x8 v;
#pragma unroll
    for (int jj = 0; jj < 8; ++jj) {
      int Kpp = 8 * (lane >> 4) + jj;
      v[jj] = (Kpp < 16) ? (short)f2bf(bfv3[16 * h + Kpp]) : (short)0;
    }
    w3b = v;
  }

  b1s[tid] = bi1[tid];
  if (tid < 32) b2s[tid] = bfv2[32 * r + tid];

  // ---- init: h0 = tanh(x0 @ Wi1 + bi1); y0 slice = h0 @ Wi2 + bi2 (fp32) ----
  {
    int row = tid >> 5, col0 = (tid & 31) * 16;
    const float* xr = x + ((16 * c + row) * LQ) * IQ;
    float xv[16];
#pragma unroll
    for (int j = 0; j < 16; ++j) xv[j] = xr[j];
    for (int cc = 0; cc < 16; ++cc) {
      int col = col0 + cc;
      float s = bi1[col];
#pragma unroll
      for (int j = 0; j < 16; ++j) s += xv[j] * Wi1[j * WQ + col];
      h0f[row][col] = tanhf(s);
    }
  }
  __syncthreads();
  if (tid < 128) {      // publish y0 slice (fp32!) cols [8r, 8r+8)
    int m = tid >> 3, hl = tid & 7;
    float s = bi2[8 * r + hl];
#pragma unroll 8
    for (int k = 0; k < WQ; ++k) s += h0f[m][k] * Wi2[k * HQ + 8 * r + hl];
    st32a((u32t*)&y0b[m * HQ + 8 * r + hl], __builtin_bit_cast(u32t, s));
  }
  drain_all();
  __syncthreads();
  if (tid == 0) st32a(fy + r, 1u);
  // gather full y0 -> per-thread fp32 state: thread t owns y[t>>5][4*(t&31)..+4)
  f32x4 y4;
  {
    pollge(fy + ((tid & 31) >> 1), 1u);
    u64t a = ld64a((const u64t*)(y0b + tid * 4));
    u64t b = ld64a((const u64t*)(y0b + tid * 4 + 2));
    y4[0] = __builtin_bit_cast(float, (u32t)a);
    y4[1] = __builtin_bit_cast(float, (u32t)(a >> 32));
    y4[2] = __builtin_bit_cast(float, (u32t)b);
    y4[3] = __builtin_bit_cast(float, (u32t)(b >> 32));
  }
  __syncthreads();     // h0f dead; pool reused

  const float* xrow = x + ((size_t)(16 * c + (tid >> 4))) * LQ * IQ + (tid & 15);
  const float* tsp  = ts + (size_t)(16 * c + tid) * LQ;

  // ======================= main scan: 1023 steps =======================
  for (int t = 0; t < LQ - 1; ++t) {
    const int A = t & 3;
    const u32t target = 16u * (u32t)((t >> 2) + 1);
    float* dyA = dyb + A * 2048;
    float* dyZ = dyb + ((t + 2) & 3) * 2048;
    u32t* cntA = (u32t*)(cb + A * 128);

    // zero own slice of the buffer used at t+2 (safe: all t-2 readers done)
    if (tid < 64) st64a((u64t*)(dyZ + r * 128 + tid * 2), 0ull);
    // issue dx/dt loads early (written to LDS after B1)
    float xa = 0.f, xb = 0.f, ta = 0.f, tb = 0.f;
    if (tid < 256) { const float* xp = xrow + t * IQ; xa = xp[0]; xb = xp[IQ]; }
    if (tid < 16)  { ta = tsp[t]; tb = tsp[t + 1]; }
    // pack y (fp32 regs -> bf16 LDS)
    {
      u32t w0 = cvtpk(y4[0], y4[1]), w1 = cvtpk(y4[2], y4[3]);
      *(u64t*)&y_s[tid >> 5][4 * (tid & 31)] = ((u64t)w1 << 32) | (u64t)w0;
    }
    __syncthreads();                                       // B1
    if (tid < 256) dxs[(tid >> 4) * 20 + (tid & 15)] = xb - xa;
    if (tid < 16)  dtl[tid] = tb - ta;
    // ---- P1: h1 = tanh(y @ Wf1 + b1), wave w -> cols [64w, 64w+64) ----
    {
      bf16x8 af[4];
#pragma unroll
      for (int k4 = 0; k4 < 4; ++k4)
        af[k4] = *(const bf16x8*)&y_s[lane & 15][32 * k4 + 8 * (lane >> 4)];
#pragma unroll
      for (int n = 0; n < 4; ++n) {
        f32x4 acc = {0.f, 0.f, 0.f, 0.f};
#pragma unroll
        for (int k4 = 0; k4 < 4; ++k4) acc = MFMA16(af[k4], w1f[n][k4], acc);
        const int col = 64 * wave + 16 * n + (lane & 15);
        const float bb = b1s[col];
#pragma unroll
        for (int i = 0; i < 4; ++i)
          h1s[4 * (lane >> 4) + i][col] = f2bf(fast_tanh(acc[i] + bb));
      }
    }
    __syncthreads();                                       // B2
    // ---- P2: h2 slice partials ----
    {
      f32x4 a0 = {0.f, 0.f, 0.f, 0.f}, a1 = {0.f, 0.f, 0.f, 0.f};
#pragma unroll
      for (int kk = 0; kk < 2; ++kk) {
        const bf16x8 f0 = *(const bf16x8*)&h1s[lane & 15][32 * (4 * w_q + kk) + 8 * (lane >> 4)];
        const bf16x8 f1 = *(const bf16x8*)&h1s[lane & 15][32 * (4 * w_q + kk + 2) + 8 * (lane >> 4)];
        a0 = MFMA16(f0, w2f[kk], a0);
        a1 = MFMA16(f1, w2f[kk + 2], a1);
      }
#pragma unroll
      for (int i = 0; i < 4; ++i)
        red[wave][4 * (lane >> 4) + i][lane & 15] = a0[i] + a1[i];
    }
    __syncthreads();                                       // B3
    if (tid < 256) {  // reduce 4 K-partials + bias + tanh -> h2s (LDS only!)
      int row = tid >> 4, cp = tid & 15;
      int c0 = 2 * cp, c1 = c0 + 1, nt = cp >> 3, l0 = c0 & 15, l1 = c1 & 15;
      float v0 = b2s[c0], v1 = b2s[c1];
#pragma unroll
      for (int q = 0; q < 4; ++q) {
        v0 += red[(q << 1) | nt][row][l0];
        v1 += red[(q << 1) | nt][row][l1];
      }
      *(u32t*)&h2s[row][c0] = (u32t)f2bf(fast_tanh(v0)) | ((u32t)f2bf(fast_tanh(v1)) << 16);
    }
    __syncthreads();                                       // B4
    // ---- P3: partial dy via K'=(k,j)=512 MFMA; atomicAdd all-reduce ----
    {
      const int b = lane & 15;
      u32t rd[16];
      {
        const uint4* hp = (const uint4*)&h2s[b][0];
        uint4 q0 = hp[0], q1 = hp[1], q2 = hp[2], q3 = hp[3];
        rd[0] = q0.x; rd[1] = q0.y; rd[2]  = q0.z; rd[3]  = q0.w;
        rd[4] = q1.x; rd[5] = q1.y; rd[6]  = q1.z; rd[7]  = q1.w;
        rd[8] = q2.x; rd[9] = q2.y; rd[10] = q2.z; rd[11] = q2.w;
        rd[12] = q3.x; rd[13] = q3.y; rd[14] = q3.z; rd[15] = q3.w;
      }
      float dxsel[8];
#pragma unroll
      for (int jj = 0; jj < 8; ++jj) {
        float lo = dxs[b * 20 + jj], hi = dxs[b * 20 + 8 + jj];
        dxsel[jj] = (lane & 16) ? hi : lo;
      }
      f32x4 acc = {0.f, 0.f, 0.f, 0.f};
#pragma unroll
      for (int kk = 0; kk < 16; ++kk) {
        u32t d = rd[kk];
        float ha = bf2f((unsigned short)(d & 0xffffu));
        float hb = bf2f((unsigned short)(d >> 16));
        float hv = (lane & 32) ? hb : ha;
        int4 ai;
        ai.x = (int)cvtpk(hv * dxsel[0], hv * dxsel[1]);
        ai.y = (int)cvtpk(hv * dxsel[2], hv * dxsel[3]);
        ai.z = (int)cvtpk(hv * dxsel[4], hv * dxsel[5]);
        ai.w = (int)cvtpk(hv * dxsel[6], hv * dxsel[7]);
        acc = MFMA16(__builtin_bit_cast(bf16x8, ai), w3f[kk], acc);
      }
      if (r == 0) {  // bias contribution, exactly once per cluster
        int4 bi4;
        if (lane & 32) {
          bi4.x = bi4.y = bi4.z = bi4.w = 0;
        } else {
          bi4.x = (int)cvtpk(dxsel[0], dxsel[1]);
          bi4.y = (int)cvtpk(dxsel[2], dxsel[3]);
          bi4.z = (int)cvtpk(dxsel[4], dxsel[5]);
          bi4.w = (int)cvtpk(dxsel[6], dxsel[7]);
        }
        acc = MFMA16(__builtin_bit_cast(bf16x8, bi4), w3b, acc);
      }
      const int g = lane >> 4, hcol = 16 * wave + b;
#pragma unroll
      for (int i = 0; i < 4; ++i)
        faddA(dyA + (4 * g + i) * HQ + hcol, acc[i]);
    }
    drain_all();
    __syncthreads();                                       // B5
    if (tid == 0) __hip_atomic_fetch_add(cntA, 1u, __ATOMIC_RELAXED, __HIP_MEMORY_SCOPE_AGENT);
    pollge(cntA, target);
    // read reduced dy (own 4 floats), update replicated fp32 y state
    {
      u64t a = ld64a((const u64t*)(dyA + tid * 4));
      u64t b = ld64a((const u64t*)(dyA + tid * 4 + 2));
      const float dtv = dtl[tid >> 5];
      y4[0] += __builtin_bit_cast(float, (u32t)a) * dtv;
      y4[1] += __builtin_bit_cast(float, (u32t)(a >> 32)) * dtv;
      y4[2] += __builtin_bit_cast(float, (u32t)b) * dtv;
      y4[3] += __builtin_bit_cast(float, (u32t)(b >> 32)) * dtv;
    }
  }

  // ---- epilogue: y is replicated fp32 in registers; block r==0 finishes ----
  if (r == 0) {
    float* yf = (float*)(pool + OFF_RED);   // f32 [16][128]
    {
      int m = tid >> 5, h4 = 4 * (tid & 31);
#pragma unroll
      for (int i = 0; i < 4; ++i) yf[m * HQ + h4 + i] = y4[i];
    }
    __syncthreads();
    float* gep = (float*)(pool + OFF_YS);   // f32 [16][32]
    {
      int m = tid >> 5, o = tid & 31;
      float s = bo1[o];
#pragma unroll 8
      for (int k = 0; k < HQ; ++k) s += yf[m * HQ + k] * Wo1[k * 32 + o];
      gep[m * 32 + o] = tanhf(s);
    }
    __syncthreads();
    if (tid < 64) {
      int m = tid >> 2, oo = tid & 3;
      float s = bo2[oo];
#pragma unroll
      for (int k = 0; k < 32; ++k) s += gep[m * 32 + k] * Wo2[k * OQ + oo];
      out[(16 * c + m) * OQ + oo] = 1.f / (1.f + __expf(-s));
    }
  }
}

extern "C" void kernel_launch(void* const* d_in, const int* in_sizes, int n_in,
                              void* d_out, int out_size, void* d_ws, size_t ws_size,
                              hipStream_t stream) {
  (void)in_sizes; (void)n_in; (void)out_size; (void)ws_size;
  // zero counters + dy buffers + init-broadcast area every call
  hipMemsetAsync(d_ws, 0, 16 * CSTRIDE, stream);
  cde_kernel<<<dim3(256), dim3(THREADS), 0, stream>>>(
      (const float*)d_in[0],  (const float*)d_in[1],
      (const float*)d_in[2],  (const float*)d_in[3],
      (const float*)d_in[4],  (const float*)d_in[5],
      (const float*)d_in[6],  (const float*)d_in[7],
      (const float*)d_in[8],  (const float*)d_in[9],
      (const float*)d_in[10], (const float*)d_in[11],
      (const float*)d_in[12], (const float*)d_in[13],
      (const float*)d_in[14], (const float*)d_in[15],
      (float*)d_out, (unsigned char*)d_ws);
}